// Round 6
// baseline (439.747 us; speedup 1.0000x reference)
//
#include <hip/hip_runtime.h>
#include <hip/hip_bf16.h>
#include <stdint.h>

#define B_  4
#define T_  300
#define U_  60
#define V_  1000
#define M_TOT (B_*T_*U_)   // 72000
#define WK  1056           // padded W row stride (shorts)
#define PK  1040           // padded proj row stride (floats)
#define HS  1056           // padded H row stride (shorts)

typedef __attribute__((ext_vector_type(8))) short short8;
typedef __attribute__((ext_vector_type(4))) float f32x4;
typedef __attribute__((ext_vector_type(4))) int int4v;

__device__ __forceinline__ short f2bf(float f) {
    union { float f; uint32_t u; } c; c.f = f;
    uint32_t u = c.u;
    uint32_t r = (u + 0x7FFFu + ((u >> 16) & 1u)) >> 16;
    return (short)r;
}

__device__ __forceinline__ float fast_tanh(float x) {
    float e = __expf(2.0f * x);
    float r = __builtin_amdgcn_rcpf(e + 1.0f);
    return 1.0f - 2.0f * r;
}

__device__ __forceinline__ void gl_lds16(const void* g, void* l) {
    __builtin_amdgcn_global_load_lds(
        (const __attribute__((address_space(1))) void*)g,
        (__attribute__((address_space(3))) void*)l, 16, 0, 0);
}

// ---------------- prep kernels ----------------

// in: fp32 [R][C] row-major -> out: bf16 [C rows][R cols], row stride ostride
__global__ void transpose_cvt(const float* __restrict__ in, short* __restrict__ out,
                              int R, int C, int ostride) {
    __shared__ float tile[64][65];
    const int tx = threadIdx.x & 63, ty = threadIdx.x >> 6;
    const int r0 = blockIdx.y * 64, c0 = blockIdx.x * 64;
#pragma unroll
    for (int i = 0; i < 16; ++i) {
        int r = r0 + i * 4 + ty, c = c0 + tx;
        float v = 0.f;
        if (r < R && c < C) v = in[(long)r * C + c];
        tile[i * 4 + ty][tx] = v;
    }
    __syncthreads();
#pragma unroll
    for (int i = 0; i < 16; ++i) {
        int oc = c0 + i * 4 + ty;
        int orr = r0 + tx;
        out[(long)oc * ostride + orr] = f2bf(tile[tx][i * 4 + ty]);
    }
}

// P[M][PK] = bf16(X[M][512]) @ Wt[k_off:k_off+512]^T (+ b1)
__global__ __launch_bounds__(256, 2) void proj_gemm(
        const float* __restrict__ X, int M, int k_off,
        const short* __restrict__ Wt,
        const float* __restrict__ b1,
        float* __restrict__ P)
{
    __shared__ short As[64 * 64];
    const int tid = threadIdx.x;
    const int lane = tid & 63;
    const int w = tid >> 6;
    const int wm = w >> 1, wn = w & 1;
    const int m0 = blockIdx.x * 64, n0 = blockIdx.y * 64;

    f32x4 acc[2][2] = {};
    for (int k0 = 0; k0 < 512; k0 += 64) {
#pragma unroll
        for (int c = 0; c < 2; ++c) {
            int lin = tid + 256 * c;
            int row = lin >> 3, k8 = lin & 7;
            int m = m0 + row;
            short vals[8];
            if (m < M) {
                const float* xp = X + (long)m * 512 + k0 + k8 * 8;
#pragma unroll
                for (int j = 0; j < 8; ++j) vals[j] = f2bf(xp[j]);
            } else {
#pragma unroll
                for (int j = 0; j < 8; ++j) vals[j] = 0;
            }
            int byte = row * 128 + k8 * 16;
            byte ^= (row & 7) << 4;
            *(int4v*)((char*)As + byte) = *(const int4v*)vals;
        }
        __syncthreads();
#pragma unroll
        for (int ks = 0; ks < 2; ++ks) {
            short8 af[2];
#pragma unroll
            for (int mf = 0; mf < 2; ++mf) {
                int row = wm * 32 + mf * 16 + (lane & 15);
                int byte = row * 128 + ks * 64 + (lane >> 4) * 16;
                byte ^= (row & 7) << 4;
                af[mf] = *(const short8*)((char*)As + byte);
            }
#pragma unroll
            for (int nf = 0; nf < 2; ++nf) {
                int h = n0 + wn * 32 + nf * 16 + (lane & 15);
                const short* bp = Wt + (long)h * WK + k_off + k0 + ks * 32 + (lane >> 4) * 8;
                short8 bfv = *(const short8*)bp;
#pragma unroll
                for (int mf = 0; mf < 2; ++mf)
                    acc[mf][nf] = __builtin_amdgcn_mfma_f32_16x16x32_bf16(af[mf], bfv, acc[mf][nf], 0, 0, 0);
            }
        }
        __syncthreads();
    }
#pragma unroll
    for (int mf = 0; mf < 2; ++mf)
#pragma unroll
        for (int nf = 0; nf < 2; ++nf) {
            int h = n0 + wn * 32 + nf * 16 + (lane & 15);
            float bb = b1 ? b1[h] : 0.f;
#pragma unroll
            for (int j = 0; j < 4; ++j) {
                int m = m0 + wm * 32 + mf * 16 + (lane >> 4) * 4 + j;
                if (m < M) P[(long)m * PK + h] = acc[mf][nf][j] + bb;
            }
        }
}

// ---------------- H materialization ----------------
// H[ml][k] = bf16(tanh(encP[bt][k] + decP[b*60+u][k])), ml local to chunk
__global__ __launch_bounds__(256) void hgen(
        const float* __restrict__ encP, const float* __restrict__ decP,
        short* __restrict__ H, int m_base, int m_count)
{
    int idx = blockIdx.x * 256 + threadIdx.x;
    int ml = idx >> 7;
    if (ml >= m_count) return;
    int kg = (idx & 127) << 3;
    int m = m_base + ml;
    int bt = m / U_;
    int u = m - bt * U_;
    int b = m / (T_ * U_);
    const float* e = encP + (long)bt * PK + kg;
    const float* d = decP + (long)(b * U_ + u) * PK + kg;
    f32x4 e0 = *(const f32x4*)(e), e1 = *(const f32x4*)(e + 4);
    f32x4 d0 = *(const f32x4*)(d), d1 = *(const f32x4*)(d + 4);
    short8 v;
#pragma unroll
    for (int j = 0; j < 4; ++j) v[j]     = f2bf(fast_tanh(e0[j] + d0[j]));
#pragma unroll
    for (int j = 0; j < 4; ++j) v[4 + j] = f2bf(fast_tanh(e1[j] + d1[j]));
    *(short8*)(H + (long)ml * HS + kg) = v;
}

// ---------------- main GEMM: out = H @ W2t^T + b2 ----------------
// 256m x 256n block, 8 waves (2m x 4n), wave tile 128x64, BK=32, K=1024.
// 4-slot LDS ring (128 KB): stage tile t+3 (global_load_lds, inverse-swizzled
// source) during tile t; gate = counted vmcnt(8) + lgkmcnt(0) + s_barrier once
// per tile. Loads stay in flight ~3 tiles (~2000 cy) -> never drained in-loop.
__global__ __launch_bounds__(512, 2) void gemm256(
        const short* __restrict__ H,    // [m_count][HS]
        const short* __restrict__ W2t,  // [1024][WK], rows >= V_ are zero
        const float* __restrict__ b2,
        float* __restrict__ out,        // [M_TOT][V_]
        int m_base, int m_count)
{
    __shared__ short lds[4][2][256 * 32];   // [ring][A,B][row*32k] 16KB each

    const int tid = threadIdx.x;
    const int lane = tid & 63;
    const int w = tid >> 6;            // 0..7
    const int wm = w >> 2, wn = w & 3;
    const int l15 = lane & 15, ksel = lane >> 4;

    // bijective XCD-aware swizzle; consecutive wg share the m-block (H reuse)
    const int nwg = gridDim.x;
    int bid = blockIdx.x;
    int q = nwg >> 3, r = nwg & 7;
    int xcd = bid & 7, lq = bid >> 3;
    int wg = (xcd < r ? xcd * (q + 1) : r * (q + 1) + (xcd - r) * q) + lq;
    const int m0 = (wg >> 2) * 256;    // chunk-local
    const int n0 = (wg & 3) * 256;

    // staging assignment: load L in {0,1}, granule index gi = L*512 + tid.
    // LDS is linear in gi; linear slot (row, g') holds source granule
    // g = g' ^ ((row>>1)&3)  (bank-balancing swizzle, same XOR on read side).
    const int giA0 = tid, giA1 = 512 + tid;
    const int rA0 = giA0 >> 2, rA1 = giA1 >> 2;
    const int gA0 = (giA0 & 3) ^ ((rA0 >> 1) & 3);
    const int gA1 = (giA1 & 3) ^ ((rA1 >> 1) & 3);
    int hr0 = m0 + rA0; if (hr0 >= m_count) hr0 = m_count - 1;
    int hr1 = m0 + rA1; if (hr1 >= m_count) hr1 = m_count - 1;
    const short* aS0 = H + (long)hr0 * HS + gA0 * 8;
    const short* aS1 = H + (long)hr1 * HS + gA1 * 8;
    const short* bS0 = W2t + (long)(n0 + rA0) * WK + gA0 * 8;
    const short* bS1 = W2t + (long)(n0 + rA1) * WK + gA1 * 8;
    const int dL0 = (w * 64) * 16;          // wave-uniform LDS byte offsets
    const int dL1 = (512 + w * 64) * 16;

#define STAGE(tt, s) do {                                              \
    gl_lds16(aS0 + (tt) * 32, (char*)&lds[(s)][0][0] + dL0);           \
    gl_lds16(aS1 + (tt) * 32, (char*)&lds[(s)][0][0] + dL1);           \
    gl_lds16(bS0 + (tt) * 32, (char*)&lds[(s)][1][0] + dL0);           \
    gl_lds16(bS1 + (tt) * 32, (char*)&lds[(s)][1][0] + dL1);           \
} while (0)

#define GATE(vm) do {                                                  \
    asm volatile("s_waitcnt vmcnt(" #vm ") lgkmcnt(0)" ::: "memory");  \
    __builtin_amdgcn_s_barrier();                                      \
    __builtin_amdgcn_sched_barrier(0);                                 \
} while (0)

    f32x4 acc[8][4] = {};

#define COMPUTE(sarg) do {                                                     \
    const char* Ab = (const char*)&lds[(sarg)][0][0];                          \
    const char* Bb = (const char*)&lds[(sarg)][1][0];                          \
    short8 bf[4];                                                              \
    _Pragma("unroll")                                                          \
    for (int nf = 0; nf < 4; ++nf) {                                           \
        int rw = wn * 64 + nf * 16 + l15;                                      \
        bf[nf] = *(const short8*)(Bb + rw * 64 + ((ksel ^ ((rw >> 1) & 3)) << 4)); \
    }                                                                          \
    _Pragma("unroll")                                                          \
    for (int qm = 0; qm < 2; ++qm) {                                           \
        short8 af[4];                                                          \
        _Pragma("unroll")                                                      \
        for (int mf = 0; mf < 4; ++mf) {                                       \
            int rw = wm * 128 + qm * 64 + mf * 16 + l15;                       \
            af[mf] = *(const short8*)(Ab + rw * 64 + ((ksel ^ ((rw >> 1) & 3)) << 4)); \
        }                                                                      \
        __builtin_amdgcn_s_setprio(1);                                         \
        _Pragma("unroll")                                                      \
        for (int nf = 0; nf < 4; ++nf)                                         \
            _Pragma("unroll")                                                  \
            for (int mf = 0; mf < 4; ++mf)                                     \
                acc[qm * 4 + mf][nf] = __builtin_amdgcn_mfma_f32_16x16x32_bf16(\
                    af[mf], bf[nf], acc[qm * 4 + mf][nf], 0, 0, 0);            \
        __builtin_amdgcn_s_setprio(0);                                         \
    }                                                                          \
} while (0)

    // prologue: stage tiles 0,1,2 into slots 0,1,2
    STAGE(0, 0); STAGE(1, 1); STAGE(2, 2);

#pragma unroll 1
    for (int tt = 0; tt < 29; ++tt) {
        GATE(8);                       // retire tile tt; keep tt+1,tt+2 in flight
        STAGE(tt + 3, (tt + 3) & 3);   // into slot freed at tile tt-1
        COMPUTE(tt & 3);
    }
    GATE(8); COMPUTE(1);               // tile 29
    GATE(4); COMPUTE(2);               // tile 30
    GATE(0); COMPUTE(3);               // tile 31

    // epilogue
#pragma unroll
    for (int nf = 0; nf < 4; ++nf) {
        int n = n0 + wn * 64 + nf * 16 + l15;
        if (n < V_) {
            float bv = b2[n];
#pragma unroll
            for (int qm = 0; qm < 2; ++qm)
#pragma unroll
                for (int mf = 0; mf < 4; ++mf)
#pragma unroll
                    for (int j = 0; j < 4; ++j) {
                        int ml = m0 + wm * 128 + qm * 64 + mf * 16 + ksel * 4 + j;
                        if (ml < m_count)
                            out[(long)(m_base + ml) * V_ + n] = acc[qm * 4 + mf][nf][j] + bv;
                    }
        }
    }
#undef STAGE
#undef GATE
#undef COMPUTE
}

// ---------------- fallback fused kernel (round-3, used only if ws too small) --
__global__ __launch_bounds__(512, 2) void joint_gemm(
        const float* __restrict__ encP, const float* __restrict__ decP,
        const short* __restrict__ W2t, const float* __restrict__ b2,
        float* __restrict__ out)
{
    __shared__ short As[2][64 * 64];
    const int tid = threadIdx.x;
    const int lane = tid & 63;
    const int w = tid >> 6;
    const int m0 = blockIdx.x * 64;
    const int n0 = blockIdx.y * 512;

    const int arow = tid >> 3;
    const int k8 = tid & 7;
    const int am = m0 + arow;
    const int bt = am / U_;
    const int u = am - bt * U_;
    const int bidx = am / (T_ * U_);
    const float* eptr = encP + (long)bt * PK + k8 * 8;
    const float* dptr = decP + (long)(bidx * U_ + u) * PK + k8 * 8;
    const int wbyte = (arow * 128 + k8 * 16) ^ ((arow & 7) << 4);

    f32x4 acc[4][4] = {};
    const short* bbase[4];
#pragma unroll
    for (int nf = 0; nf < 4; ++nf) {
        int n = n0 + w * 64 + nf * 16 + (lane & 15);
        bbase[nf] = W2t + (long)n * WK + (lane >> 4) * 8;
    }
    f32x4 e0 = *(const f32x4*)(eptr), e1 = *(const f32x4*)(eptr + 4);
    f32x4 d0 = *(const f32x4*)(dptr), d1 = *(const f32x4*)(dptr + 4);
    {
        short vals[8];
#pragma unroll
        for (int j = 0; j < 4; ++j) vals[j]     = f2bf(fast_tanh(e0[j] + d0[j]));
#pragma unroll
        for (int j = 0; j < 4; ++j) vals[4 + j] = f2bf(fast_tanh(e1[j] + d1[j]));
        *(int4v*)((char*)&As[0][0] + wbyte) = *(const int4v*)vals;
    }
    e0 = *(const f32x4*)(eptr + 64); e1 = *(const f32x4*)(eptr + 68);
    d0 = *(const f32x4*)(dptr + 64); d1 = *(const f32x4*)(dptr + 68);
    asm volatile("s_waitcnt lgkmcnt(0)" ::: "memory");
    __builtin_amdgcn_s_barrier();

#pragma unroll 1
    for (int t = 0; t < 16; ++t) {
        const int k0 = t * 64;
        short8 bfr[2][4];
#pragma unroll
        for (int ks = 0; ks < 2; ++ks)
#pragma unroll
            for (int nf = 0; nf < 4; ++nf)
                bfr[ks][nf] = *(const short8*)(bbase[nf] + k0 + ks * 32);
        if (t < 15) {
            short vals[8];
#pragma unroll
            for (int j = 0; j < 4; ++j) vals[j]     = f2bf(fast_tanh(e0[j] + d0[j]));
#pragma unroll
            for (int j = 0; j < 4; ++j) vals[4 + j] = f2bf(fast_tanh(e1[j] + d1[j]));
            *(int4v*)((char*)&As[(t & 1) ^ 1][0] + wbyte) = *(const int4v*)vals;
            if (t < 14) {
                e0 = *(const f32x4*)(eptr + k0 + 128); e1 = *(const f32x4*)(eptr + k0 + 132);
                d0 = *(const f32x4*)(dptr + k0 + 128); d1 = *(const f32x4*)(dptr + k0 + 132);
            }
        }
        const char* rb = (const char*)&As[t & 1][0];
#pragma unroll
        for (int ks = 0; ks < 2; ++ks) {
            short8 af[4];
#pragma unroll
            for (int mf = 0; mf < 4; ++mf) {
                int row = mf * 16 + (lane & 15);
                int byte = (row * 128 + ks * 64 + (lane >> 4) * 16) ^ ((row & 7) << 4);
                af[mf] = *(const short8*)(rb + byte);
            }
#pragma unroll
            for (int nf = 0; nf < 4; ++nf)
#pragma unroll
                for (int mf = 0; mf < 4; ++mf)
                    acc[mf][nf] = __builtin_amdgcn_mfma_f32_16x16x32_bf16(
                        af[mf], bfr[ks][nf], acc[mf][nf], 0, 0, 0);
        }
        if (t < 15) {
            asm volatile("s_waitcnt lgkmcnt(0)" ::: "memory");
            __builtin_amdgcn_s_barrier();
        }
    }
#pragma unroll
    for (int nf = 0; nf < 4; ++nf) {
        int n = n0 + w * 64 + nf * 16 + (lane & 15);
        float bv = (n < V_) ? b2[n] : 0.f;
#pragma unroll
        for (int mf = 0; mf < 4; ++mf)
#pragma unroll
            for (int j = 0; j < 4; ++j) {
                int m = m0 + mf * 16 + (lane >> 4) * 4 + j;
                if (n < V_)
                    out[(long)m * V_ + n] = acc[mf][nf][j] + bv;
            }
    }
}

// ---------------- launch ----------------
extern "C" void kernel_launch(void* const* d_in, const int* in_sizes, int n_in,
                              void* d_out, int out_size, void* d_ws, size_t ws_size,
                              hipStream_t stream) {
    const float* enc = (const float*)d_in[0];
    const float* dec = (const float*)d_in[1];
    const float* W1  = (const float*)d_in[2];
    const float* b1  = (const float*)d_in[3];
    const float* W2  = (const float*)d_in[4];
    const float* b2  = (const float*)d_in[5];
    float* out = (float*)d_out;

    char* ws = (char*)d_ws;
    size_t off = 0;
    short* W1t  = (short*)(ws + off); off += (size_t)1024 * WK * 2;
    short* W2t  = (short*)(ws + off); off += (size_t)1024 * WK * 2;
    float* encP = (float*)(ws + off); off += (size_t)1200 * PK * 4;
    float* decP = (float*)(ws + off); off += (size_t)240 * PK * 4;
    short* Hbuf = (short*)(ws + off);

    transpose_cvt<<<dim3(16, 16), 256, 0, stream>>>(W1, W1t, 1024, 1024, WK);
    transpose_cvt<<<dim3(16, 16), 256, 0, stream>>>(W2, W2t, 1024, 1000, WK);
    proj_gemm<<<dim3(19, 16), 256, 0, stream>>>(enc, 1200, 0,   W1t, nullptr, encP);
    proj_gemm<<<dim3(4, 16),  256, 0, stream>>>(dec, 240,  512, W1t, b1,      decP);

    long avail = (long)ws_size - (long)off;
    long rows = avail > 0 ? avail / (HS * 2) : 0;
    if (rows > M_TOT) rows = M_TOT;
    rows &= ~255L;

    if (rows >= 8192) {
        for (long mb = 0; mb < M_TOT; mb += rows) {
            int mc = (int)((M_TOT - mb < rows) ? (M_TOT - mb) : rows);
            hgen<<<(mc * 128 + 255) / 256, 256, 0, stream>>>(encP, decP, Hbuf, (int)mb, mc);
            int gx = ((mc + 255) / 256) * 4;
            gemm256<<<gx, 512, 0, stream>>>(Hbuf, W2t, b2, out, (int)mb, mc);
        }
    } else {
        joint_gemm<<<dim3(1125, 2), 512, 0, stream>>>(encP, decP, W2t, b2, out);
    }
}

// Round 7
// 425.484 us; speedup vs baseline: 1.0335x; 1.0335x over previous
//
#include <hip/hip_runtime.h>
#include <hip/hip_bf16.h>
#include <stdint.h>

#define B_  4
#define T_  300
#define U_  60
#define V_  1000
#define M_TOT (B_*T_*U_)   // 72000
#define WK  1056           // padded W row stride (shorts)
#define PK  1040           // padded proj row stride (floats)
#define HS  1056           // padded H row stride (shorts)

typedef __attribute__((ext_vector_type(8))) short short8;
typedef __attribute__((ext_vector_type(4))) float f32x4;
typedef __attribute__((ext_vector_type(4))) int int4v;

__device__ __forceinline__ short f2bf(float f) {
    union { float f; uint32_t u; } c; c.f = f;
    uint32_t u = c.u;
    uint32_t r = (u + 0x7FFFu + ((u >> 16) & 1u)) >> 16;
    return (short)r;
}

__device__ __forceinline__ float fast_tanh(float x) {
    float e = __expf(2.0f * x);
    float r = __builtin_amdgcn_rcpf(e + 1.0f);
    return 1.0f - 2.0f * r;
}

__device__ __forceinline__ void gl_lds16(const void* g, void* l) {
    __builtin_amdgcn_global_load_lds(
        (const __attribute__((address_space(1))) void*)g,
        (__attribute__((address_space(3))) void*)l, 16, 0, 0);
}

// ---------------- prep kernels ----------------

__global__ void transpose_cvt(const float* __restrict__ in, short* __restrict__ out,
                              int R, int C, int ostride) {
    __shared__ float tile[64][65];
    const int tx = threadIdx.x & 63, ty = threadIdx.x >> 6;
    const int r0 = blockIdx.y * 64, c0 = blockIdx.x * 64;
#pragma unroll
    for (int i = 0; i < 16; ++i) {
        int r = r0 + i * 4 + ty, c = c0 + tx;
        float v = 0.f;
        if (r < R && c < C) v = in[(long)r * C + c];
        tile[i * 4 + ty][tx] = v;
    }
    __syncthreads();
#pragma unroll
    for (int i = 0; i < 16; ++i) {
        int oc = c0 + i * 4 + ty;
        int orr = r0 + tx;
        out[(long)oc * ostride + orr] = f2bf(tile[tx][i * 4 + ty]);
    }
}

__global__ __launch_bounds__(256, 2) void proj_gemm(
        const float* __restrict__ X, int M, int k_off,
        const short* __restrict__ Wt,
        const float* __restrict__ b1,
        float* __restrict__ P)
{
    __shared__ short As[64 * 64];
    const int tid = threadIdx.x;
    const int lane = tid & 63;
    const int w = tid >> 6;
    const int wm = w >> 1, wn = w & 1;
    const int m0 = blockIdx.x * 64, n0 = blockIdx.y * 64;

    f32x4 acc[2][2] = {};
    for (int k0 = 0; k0 < 512; k0 += 64) {
#pragma unroll
        for (int c = 0; c < 2; ++c) {
            int lin = tid + 256 * c;
            int row = lin >> 3, k8 = lin & 7;
            int m = m0 + row;
            short vals[8];
            if (m < M) {
                const float* xp = X + (long)m * 512 + k0 + k8 * 8;
#pragma unroll
                for (int j = 0; j < 8; ++j) vals[j] = f2bf(xp[j]);
            } else {
#pragma unroll
                for (int j = 0; j < 8; ++j) vals[j] = 0;
            }
            int byte = row * 128 + k8 * 16;
            byte ^= (row & 7) << 4;
            *(int4v*)((char*)As + byte) = *(const int4v*)vals;
        }
        __syncthreads();
#pragma unroll
        for (int ks = 0; ks < 2; ++ks) {
            short8 af[2];
#pragma unroll
            for (int mf = 0; mf < 2; ++mf) {
                int row = wm * 32 + mf * 16 + (lane & 15);
                int byte = row * 128 + ks * 64 + (lane >> 4) * 16;
                byte ^= (row & 7) << 4;
                af[mf] = *(const short8*)((char*)As + byte);
            }
#pragma unroll
            for (int nf = 0; nf < 2; ++nf) {
                int h = n0 + wn * 32 + nf * 16 + (lane & 15);
                const short* bp = Wt + (long)h * WK + k_off + k0 + ks * 32 + (lane >> 4) * 8;
                short8 bfv = *(const short8*)bp;
#pragma unroll
                for (int mf = 0; mf < 2; ++mf)
                    acc[mf][nf] = __builtin_amdgcn_mfma_f32_16x16x32_bf16(af[mf], bfv, acc[mf][nf], 0, 0, 0);
            }
        }
        __syncthreads();
    }
#pragma unroll
    for (int mf = 0; mf < 2; ++mf)
#pragma unroll
        for (int nf = 0; nf < 2; ++nf) {
            int h = n0 + wn * 32 + nf * 16 + (lane & 15);
            float bb = b1 ? b1[h] : 0.f;
#pragma unroll
            for (int j = 0; j < 4; ++j) {
                int m = m0 + wm * 32 + mf * 16 + (lane >> 4) * 4 + j;
                if (m < M) P[(long)m * PK + h] = acc[mf][nf][j] + bb;
            }
        }
}

// ---------------- H materialization ----------------
__global__ __launch_bounds__(256) void hgen(
        const float* __restrict__ encP, const float* __restrict__ decP,
        short* __restrict__ H, int m_base, int m_count)
{
    int idx = blockIdx.x * 256 + threadIdx.x;
    int ml = idx >> 7;
    if (ml >= m_count) return;
    int kg = (idx & 127) << 3;
    int m = m_base + ml;
    int bt = m / U_;
    int u = m - bt * U_;
    int b = m / (T_ * U_);
    const float* e = encP + (long)bt * PK + kg;
    const float* d = decP + (long)(b * U_ + u) * PK + kg;
    f32x4 e0 = *(const f32x4*)(e), e1 = *(const f32x4*)(e + 4);
    f32x4 d0 = *(const f32x4*)(d), d1 = *(const f32x4*)(d + 4);
    short8 v;
#pragma unroll
    for (int j = 0; j < 4; ++j) v[j]     = f2bf(fast_tanh(e0[j] + d0[j]));
#pragma unroll
    for (int j = 0; j < 4; ++j) v[4 + j] = f2bf(fast_tanh(e1[j] + d1[j]));
    *(short8*)(H + (long)ml * HS + kg) = v;
}

// ---------------- main GEMM: out = H @ W2t^T + b2 ----------------
// 256m x 256n, 8 waves (2m x 4n), wave tile 128x64, BK=32, K=1024 (32 tiles).
// 4-slot LDS ring (32KB/slot, 128KB). TWO phases per K-tile, each:
//   {ds_read 4-8 b128; stage 2 gl_lds (tile t+3); [vmcnt(8) gate, ph B];
//    s_barrier; lgkmcnt(0); setprio(1); 16 MFMA; setprio(0); s_barrier}
// Steady state: 12 gl_lds outstanding, gate(8) retires exactly tile t+1's 4
// units (staged 2 tiles earlier) -> loads never drained to 0 in the loop.
__global__ __launch_bounds__(512, 2) void gemm256(
        const short* __restrict__ H,    // [m_count][HS]
        const short* __restrict__ W2t,  // [1024][WK], rows >= V_ zero
        const float* __restrict__ b2,
        float* __restrict__ out,        // [M_TOT][V_]
        int m_base, int m_count)
{
    __shared__ __align__(16) char lds[4 * 32768];  // slot: A[256*64B] + B[256*64B]

    const int tid = threadIdx.x;
    const int lane = tid & 63;
    const int w = tid >> 6;            // 0..7
    const int wm = w >> 2, wn = w & 3;
    const int l15 = lane & 15, ksel = lane >> 4;

    // bijective XCD-aware swizzle; wg>>2 = m-block, wg&3 = n-block
    const int nwg = gridDim.x;
    int bid = blockIdx.x;
    int q = nwg >> 3, r = nwg & 7;
    int xcd = bid & 7, lq = bid >> 3;
    int wg = (xcd < r ? xcd * (q + 1) : r * (q + 1) + (xcd - r) * q) + lq;
    const int m0 = (wg >> 2) * 256;
    const int n0 = (wg & 3) * 256;

    // stage sources: unit = 128 rows x 64B, 1 gl_lds/thread/unit.
    // linear LDS granule (row, g') holds global granule g = g' ^ ((row>>1)&3).
    const int srow = tid >> 2;                 // 0..127
    const int g = (tid & 3) ^ ((srow >> 1) & 3);
    int ha0 = m0 + srow;       if (ha0 >= m_count) ha0 = m_count - 1;
    int ha1 = m0 + 128 + srow; if (ha1 >= m_count) ha1 = m_count - 1;
    const short* sA0 = H + (long)ha0 * HS + g * 8;
    const short* sA1 = H + (long)ha1 * HS + g * 8;
    const short* sB0 = W2t + (long)(n0 + srow) * WK + g * 8;
    const short* sB1 = W2t + (long)(n0 + 128 + srow) * WK + g * 8;
    const int ldsoff = (w * 64) * 16;          // wave-uniform base within a unit

    f32x4 acc[8][4] = {};
    short8 bf[4];

#define PH_A(sl, ft, DOSTAGE) do {                                             \
    const char* Ab_ = (const char*)lds + (sl) * 32768;                         \
    const char* Bb_ = Ab_ + 16384;                                             \
    _Pragma("unroll")                                                          \
    for (int nf = 0; nf < 4; ++nf) {                                           \
        int rw = wn * 64 + nf * 16 + l15;                                      \
        bf[nf] = *(const short8*)(Bb_ + rw * 64 + ((ksel ^ ((rw >> 1) & 3)) << 4)); \
    }                                                                          \
    short8 af_[4];                                                             \
    _Pragma("unroll")                                                          \
    for (int mf = 0; mf < 4; ++mf) {                                           \
        int rw = wm * 128 + mf * 16 + l15;                                     \
        af_[mf] = *(const short8*)(Ab_ + rw * 64 + ((ksel ^ ((rw >> 1) & 3)) << 4)); \
    }                                                                          \
    if (DOSTAGE) {                                                             \
        char* d_ = (char*)lds + ((ft) & 3) * 32768 + ldsoff;                   \
        gl_lds16(sA0 + (ft) * 32, d_);                                         \
        gl_lds16(sA1 + (ft) * 32, d_ + 8192);                                  \
    }                                                                          \
    __builtin_amdgcn_s_barrier();                                              \
    asm volatile("s_waitcnt lgkmcnt(0)" ::: "memory");                         \
    __builtin_amdgcn_s_setprio(1);                                             \
    _Pragma("unroll")                                                          \
    for (int nf = 0; nf < 4; ++nf)                                             \
        _Pragma("unroll")                                                      \
        for (int mf = 0; mf < 4; ++mf)                                         \
            acc[mf][nf] = __builtin_amdgcn_mfma_f32_16x16x32_bf16(             \
                af_[mf], bf[nf], acc[mf][nf], 0, 0, 0);                        \
    __builtin_amdgcn_s_setprio(0);                                             \
    __builtin_amdgcn_s_barrier();                                              \
} while (0)

#define PH_B(sl, ft, DOSTAGE, GATE) do {                                       \
    const char* Ab_ = (const char*)lds + (sl) * 32768;                         \
    short8 af_[4];                                                             \
    _Pragma("unroll")                                                          \
    for (int mf = 0; mf < 4; ++mf) {                                           \
        int rw = wm * 128 + 64 + mf * 16 + l15;                                \
        af_[mf] = *(const short8*)(Ab_ + rw * 64 + ((ksel ^ ((rw >> 1) & 3)) << 4)); \
    }                                                                          \
    if (DOSTAGE) {                                                             \
        char* d_ = (char*)lds + ((ft) & 3) * 32768 + 16384 + ldsoff;           \
        gl_lds16(sB0 + (ft) * 32, d_);                                         \
        gl_lds16(sB1 + (ft) * 32, d_ + 8192);                                  \
    }                                                                          \
    GATE                                                                       \
    __builtin_amdgcn_s_barrier();                                              \
    asm volatile("s_waitcnt lgkmcnt(0)" ::: "memory");                         \
    __builtin_amdgcn_s_setprio(1);                                             \
    _Pragma("unroll")                                                          \
    for (int nf = 0; nf < 4; ++nf)                                             \
        _Pragma("unroll")                                                      \
        for (int mf = 0; mf < 4; ++mf)                                         \
            acc[4 + mf][nf] = __builtin_amdgcn_mfma_f32_16x16x32_bf16(         \
                af_[mf], bf[nf], acc[4 + mf][nf], 0, 0, 0);                    \
    __builtin_amdgcn_s_setprio(0);                                             \
    __builtin_amdgcn_s_barrier();                                              \
} while (0)

#define GATE8 asm volatile("s_waitcnt vmcnt(8)" ::: "memory");
#define GATE4 asm volatile("s_waitcnt vmcnt(4)" ::: "memory");
#define GATE0 asm volatile("s_waitcnt vmcnt(0)" ::: "memory");
#define NOGATE

    // prologue: stage tiles 0,1,2 (tile-major issue order), wait tile 0
#pragma unroll
    for (int tt = 0; tt < 3; ++tt) {
        char* dA = (char*)lds + tt * 32768 + ldsoff;
        char* dB = dA + 16384;
        gl_lds16(sA0 + tt * 32, dA);
        gl_lds16(sA1 + tt * 32, dA + 8192);
        gl_lds16(sB0 + tt * 32, dB);
        gl_lds16(sB1 + tt * 32, dB + 8192);
    }
    asm volatile("s_waitcnt vmcnt(8)" ::: "memory");
    __builtin_amdgcn_s_barrier();

#pragma unroll 1
    for (int t = 0; t < 29; ++t) {
        const int s = t & 3;
        PH_A(s, t + 3, true);
        PH_B(s, t + 3, true, GATE8);
    }
    PH_A(1, 0, false); PH_B(1, 0, false, GATE4);   // t = 29
    PH_A(2, 0, false); PH_B(2, 0, false, GATE0);   // t = 30
    PH_A(3, 0, false); PH_B(3, 0, false, NOGATE);  // t = 31

    // epilogue: + b2, store fp32
#pragma unroll
    for (int nf = 0; nf < 4; ++nf) {
        int n = n0 + wn * 64 + nf * 16 + l15;
        if (n < V_) {
            float bv = b2[n];
#pragma unroll
            for (int qm = 0; qm < 2; ++qm)
#pragma unroll
                for (int mf = 0; mf < 4; ++mf)
#pragma unroll
                    for (int j = 0; j < 4; ++j) {
                        int ml = m0 + wm * 128 + qm * 64 + mf * 16 + ksel * 4 + j;
                        if (ml < m_count)
                            out[(long)(m_base + ml) * V_ + n] = acc[qm * 4 + mf][nf][j] + bv;
                    }
        }
    }
#undef PH_A
#undef PH_B
#undef GATE8
#undef GATE4
#undef GATE0
#undef NOGATE
}

// ---------------- fallback fused kernel (only if ws too small) ----------------
__global__ __launch_bounds__(512, 2) void joint_gemm(
        const float* __restrict__ encP, const float* __restrict__ decP,
        const short* __restrict__ W2t, const float* __restrict__ b2,
        float* __restrict__ out)
{
    __shared__ short As[2][64 * 64];
    const int tid = threadIdx.x;
    const int lane = tid & 63;
    const int w = tid >> 6;
    const int m0 = blockIdx.x * 64;
    const int n0 = blockIdx.y * 512;

    const int arow = tid >> 3;
    const int k8 = tid & 7;
    const int am = m0 + arow;
    const int bt = am / U_;
    const int u = am - bt * U_;
    const int bidx = am / (T_ * U_);
    const float* eptr = encP + (long)bt * PK + k8 * 8;
    const float* dptr = decP + (long)(bidx * U_ + u) * PK + k8 * 8;
    const int wbyte = (arow * 128 + k8 * 16) ^ ((arow & 7) << 4);

    f32x4 acc[4][4] = {};
    const short* bbase[4];
#pragma unroll
    for (int nf = 0; nf < 4; ++nf) {
        int n = n0 + w * 64 + nf * 16 + (lane & 15);
        bbase[nf] = W2t + (long)n * WK + (lane >> 4) * 8;
    }
    f32x4 e0 = *(const f32x4*)(eptr), e1 = *(const f32x4*)(eptr + 4);
    f32x4 d0 = *(const f32x4*)(dptr), d1 = *(const f32x4*)(dptr + 4);
    {
        short vals[8];
#pragma unroll
        for (int j = 0; j < 4; ++j) vals[j]     = f2bf(fast_tanh(e0[j] + d0[j]));
#pragma unroll
        for (int j = 0; j < 4; ++j) vals[4 + j] = f2bf(fast_tanh(e1[j] + d1[j]));
        *(int4v*)((char*)&As[0][0] + wbyte) = *(const int4v*)vals;
    }
    e0 = *(const f32x4*)(eptr + 64); e1 = *(const f32x4*)(eptr + 68);
    d0 = *(const f32x4*)(dptr + 64); d1 = *(const f32x4*)(dptr + 68);
    asm volatile("s_waitcnt lgkmcnt(0)" ::: "memory");
    __builtin_amdgcn_s_barrier();

#pragma unroll 1
    for (int t = 0; t < 16; ++t) {
        const int k0 = t * 64;
        short8 bfr[2][4];
#pragma unroll
        for (int ks = 0; ks < 2; ++ks)
#pragma unroll
            for (int nf = 0; nf < 4; ++nf)
                bfr[ks][nf] = *(const short8*)(bbase[nf] + k0 + ks * 32);
        if (t < 15) {
            short vals[8];
#pragma unroll
            for (int j = 0; j < 4; ++j) vals[j]     = f2bf(fast_tanh(e0[j] + d0[j]));
#pragma unroll
            for (int j = 0; j < 4; ++j) vals[4 + j] = f2bf(fast_tanh(e1[j] + d1[j]));
            *(int4v*)((char*)&As[(t & 1) ^ 1][0] + wbyte) = *(const int4v*)vals;
            if (t < 14) {
                e0 = *(const f32x4*)(eptr + k0 + 128); e1 = *(const f32x4*)(eptr + k0 + 132);
                d0 = *(const f32x4*)(dptr + k0 + 128); d1 = *(const f32x4*)(dptr + k0 + 132);
            }
        }
        const char* rb = (const char*)&As[t & 1][0];
#pragma unroll
        for (int ks = 0; ks < 2; ++ks) {
            short8 af[4];
#pragma unroll
            for (int mf = 0; mf < 4; ++mf) {
                int row = mf * 16 + (lane & 15);
                int byte = (row * 128 + ks * 64 + (lane >> 4) * 16) ^ ((row & 7) << 4);
                af[mf] = *(const short8*)(rb + byte);
            }
#pragma unroll
            for (int nf = 0; nf < 4; ++nf)
#pragma unroll
                for (int mf = 0; mf < 4; ++mf)
                    acc[mf][nf] = __builtin_amdgcn_mfma_f32_16x16x32_bf16(
                        af[mf], bfr[ks][nf], acc[mf][nf], 0, 0, 0);
        }
        if (t < 15) {
            asm volatile("s_waitcnt lgkmcnt(0)" ::: "memory");
            __builtin_amdgcn_s_barrier();
        }
    }
#pragma unroll
    for (int nf = 0; nf < 4; ++nf) {
        int n = n0 + w * 64 + nf * 16 + (lane & 15);
        float bv = (n < V_) ? b2[n] : 0.f;
#pragma unroll
        for (int mf = 0; mf < 4; ++mf)
#pragma unroll
            for (int j = 0; j < 4; ++j) {
                int m = m0 + mf * 16 + (lane >> 4) * 4 + j;
                if (n < V_)
                    out[(long)m * V_ + n] = acc[mf][nf][j] + bv;
            }
    }
}

// ---------------- launch ----------------
extern "C" void kernel_launch(void* const* d_in, const int* in_sizes, int n_in,
                              void* d_out, int out_size, void* d_ws, size_t ws_size,
                              hipStream_t stream) {
    const float* enc = (const float*)d_in[0];
    const float* dec = (const float*)d_in[1];
    const float* W1  = (const float*)d_in[2];
    const float* b1  = (const float*)d_in[3];
    const float* W2  = (const float*)d_in[4];
    const float* b2  = (const float*)d_in[5];
    float* out = (float*)d_out;

    char* ws = (char*)d_ws;
    size_t off = 0;
    short* W1t  = (short*)(ws + off); off += (size_t)1024 * WK * 2;
    short* W2t  = (short*)(ws + off); off += (size_t)1024 * WK * 2;
    float* encP = (float*)(ws + off); off += (size_t)1200 * PK * 4;
    float* decP = (float*)(ws + off); off += (size_t)240 * PK * 4;
    short* Hbuf = (short*)(ws + off);

    transpose_cvt<<<dim3(16, 16), 256, 0, stream>>>(W1, W1t, 1024, 1024, WK);
    transpose_cvt<<<dim3(16, 16), 256, 0, stream>>>(W2, W2t, 1024, 1000, WK);
    proj_gemm<<<dim3(19, 16), 256, 0, stream>>>(enc, 1200, 0,   W1t, nullptr, encP);
    proj_gemm<<<dim3(4, 16),  256, 0, stream>>>(dec, 240,  512, W1t, b1,      decP);

    long avail = (long)ws_size - (long)off;
    long rows = avail > 0 ? avail / (HS * 2) : 0;
    if (rows > M_TOT) rows = M_TOT;
    rows &= ~255L;

    if (rows >= 8192) {
        for (long mb = 0; mb < M_TOT; mb += rows) {
            int mc = (int)((M_TOT - mb < rows) ? (M_TOT - mb) : rows);
            hgen<<<(mc * 128 + 255) / 256, 256, 0, stream>>>(encP, decP, Hbuf, (int)mb, mc);
            int gx = ((mc + 255) / 256) * 4;
            gemm256<<<gx, 512, 0, stream>>>(Hbuf, W2t, b2, out, (int)mb, mc);
        }
    } else {
        joint_gemm<<<dim3(1125, 2), 512, 0, stream>>>(encP, decP, W2t, b2, out);
    }
}

// Round 8
// 362.413 us; speedup vs baseline: 1.2134x; 1.1740x over previous
//
#include <hip/hip_runtime.h>
#include <hip/hip_bf16.h>
#include <stdint.h>

#define B_  4
#define T_  300
#define U_  60
#define V_  1000
#define M_TOT (B_*T_*U_)   // 72000
#define MB_CNT 563         // ceil(72000/128)
#define WK  1056           // padded W row stride (shorts) - W1t only
#define PK  1040           // padded proj row stride (floats)

typedef __attribute__((ext_vector_type(8))) short short8;
typedef __attribute__((ext_vector_type(4))) float f32x4;
typedef __attribute__((ext_vector_type(4))) int int4v;

__device__ __forceinline__ short f2bf(float f) {
    union { float f; uint32_t u; } c; c.f = f;
    uint32_t u = c.u;
    uint32_t r = (u + 0x7FFFu + ((u >> 16) & 1u)) >> 16;
    return (short)r;
}

__device__ __forceinline__ float fast_tanh(float x) {
    float e = __expf(2.0f * x);
    float r = __builtin_amdgcn_rcpf(e + 1.0f);
    return 1.0f - 2.0f * r;
}

__device__ __forceinline__ void gl_lds16(const void* g, void* l) {
    __builtin_amdgcn_global_load_lds(
        (const __attribute__((address_space(1))) void*)g,
        (__attribute__((address_space(3))) void*)l, 16, 0, 0);
}

// ---------------- prep kernels ----------------

// fp32 [R][C] -> bf16 [C][R] with row stride ostride (used for W1)
__global__ void transpose_cvt(const float* __restrict__ in, short* __restrict__ out,
                              int R, int C, int ostride) {
    __shared__ float tile[64][65];
    const int tx = threadIdx.x & 63, ty = threadIdx.x >> 6;
    const int r0 = blockIdx.y * 64, c0 = blockIdx.x * 64;
#pragma unroll
    for (int i = 0; i < 16; ++i) {
        int r = r0 + i * 4 + ty, c = c0 + tx;
        float v = 0.f;
        if (r < R && c < C) v = in[(long)r * C + c];
        tile[i * 4 + ty][tx] = v;
    }
    __syncthreads();
#pragma unroll
    for (int i = 0; i < 16; ++i) {
        int oc = c0 + i * 4 + ty;
        int orr = r0 + tx;
        out[(long)oc * ostride + orr] = f2bf(tile[tx][i * 4 + ty]);
    }
}

// W2 [1024 k][1000 v] -> packed bf16 units: W2p[(nb*32+kt)*8192 + prow*32 + ks]
__global__ void transpose_pack_w2(const float* __restrict__ in, short* __restrict__ out) {
    __shared__ float tile[64][65];
    const int tx = threadIdx.x & 63, ty = threadIdx.x >> 6;
    const int r0 = blockIdx.y * 64, c0 = blockIdx.x * 64;   // r=k, c=v
#pragma unroll
    for (int i = 0; i < 16; ++i) {
        int r = r0 + i * 4 + ty, c = c0 + tx;
        float v = 0.f;
        if (c < V_) v = in[(long)r * V_ + c];
        tile[i * 4 + ty][tx] = v;
    }
    __syncthreads();
#pragma unroll
    for (int i = 0; i < 16; ++i) {
        int oc = c0 + i * 4 + ty;       // v index 0..1023
        int orr = r0 + tx;              // k index 0..1023
        int nb = oc >> 8, prow = oc & 255, kt = orr >> 5, ks = orr & 31;
        out[(long)(nb * 32 + kt) * 8192 + prow * 32 + ks] = f2bf(tile[tx][i * 4 + ty]);
    }
}

// P[M][PK] = bf16(X[M][512]) @ W1t[k_off:k_off+512]^T (+ b1)
__global__ __launch_bounds__(256, 2) void proj_gemm(
        const float* __restrict__ X, int M, int k_off,
        const short* __restrict__ Wt,
        const float* __restrict__ b1,
        float* __restrict__ P)
{
    __shared__ short As[64 * 64];
    const int tid = threadIdx.x;
    const int lane = tid & 63;
    const int w = tid >> 6;
    const int wm = w >> 1, wn = w & 1;
    const int m0 = blockIdx.x * 64, n0 = blockIdx.y * 64;

    f32x4 acc[2][2] = {};
    for (int k0 = 0; k0 < 512; k0 += 64) {
#pragma unroll
        for (int c = 0; c < 2; ++c) {
            int lin = tid + 256 * c;
            int row = lin >> 3, k8 = lin & 7;
            int m = m0 + row;
            short vals[8];
            if (m < M) {
                const float* xp = X + (long)m * 512 + k0 + k8 * 8;
#pragma unroll
                for (int j = 0; j < 8; ++j) vals[j] = f2bf(xp[j]);
            } else {
#pragma unroll
                for (int j = 0; j < 8; ++j) vals[j] = 0;
            }
            int byte = row * 128 + k8 * 16;
            byte ^= (row & 7) << 4;
            *(int4v*)((char*)As + byte) = *(const int4v*)vals;
        }
        __syncthreads();
#pragma unroll
        for (int ks = 0; ks < 2; ++ks) {
            short8 af[2];
#pragma unroll
            for (int mf = 0; mf < 2; ++mf) {
                int row = wm * 32 + mf * 16 + (lane & 15);
                int byte = row * 128 + ks * 64 + (lane >> 4) * 16;
                byte ^= (row & 7) << 4;
                af[mf] = *(const short8*)((char*)As + byte);
            }
#pragma unroll
            for (int nf = 0; nf < 2; ++nf) {
                int h = n0 + wn * 32 + nf * 16 + (lane & 15);
                const short* bp = Wt + (long)h * WK + k_off + k0 + ks * 32 + (lane >> 4) * 8;
                short8 bfv = *(const short8*)bp;
#pragma unroll
                for (int mf = 0; mf < 2; ++mf)
                    acc[mf][nf] = __builtin_amdgcn_mfma_f32_16x16x32_bf16(af[mf], bfv, acc[mf][nf], 0, 0, 0);
            }
        }
        __syncthreads();
    }
#pragma unroll
    for (int mf = 0; mf < 2; ++mf)
#pragma unroll
        for (int nf = 0; nf < 2; ++nf) {
            int h = n0 + wn * 32 + nf * 16 + (lane & 15);
            float bb = b1 ? b1[h] : 0.f;
#pragma unroll
            for (int j = 0; j < 4; ++j) {
                int m = m0 + wm * 32 + mf * 16 + (lane >> 4) * 4 + j;
                if (m < M) P[(long)m * PK + h] = acc[mf][nf][j] + bb;
            }
        }
}

// ---------------- packed H materialization ----------------
// unit u = mb*32+kt: 128 rows x 32 shorts (8KB). thread -> one 16B granule.
// Perfect store coalescing: consecutive tid -> consecutive 16B.
__global__ __launch_bounds__(256) void hgen_pk(
        const float* __restrict__ encP, const float* __restrict__ decP,
        short* __restrict__ Hp)
{
    long idx = (long)blockIdx.x * 256 + threadIdx.x;
    int u = (int)(idx >> 9);           // unit: 0 .. 563*32-1
    int gi = (int)(idx & 511);
    int mb = u >> 5, kt = u & 31;
    int r = gi >> 2, g = gi & 3;
    int m = mb * 128 + r;
    int k = kt * 32 + g * 8;
    short8 v = {};
    if (m < M_TOT) {
        int bt = m / U_;
        int uu = m - bt * U_;
        int b = m / (T_ * U_);
        const float* e = encP + (long)bt * PK + k;
        const float* d = decP + (long)(b * U_ + uu) * PK + k;
        f32x4 e0 = *(const f32x4*)(e), e1 = *(const f32x4*)(e + 4);
        f32x4 d0 = *(const f32x4*)(d), d1 = *(const f32x4*)(d + 4);
#pragma unroll
        for (int j = 0; j < 4; ++j) v[j]     = f2bf(fast_tanh(e0[j] + d0[j]));
#pragma unroll
        for (int j = 0; j < 4; ++j) v[4 + j] = f2bf(fast_tanh(e1[j] + d1[j]));
    }
    *(short8*)(Hp + (long)u * 4096 + gi * 8) = v;
}

// ---------------- main GEMM: out = Hp @ W2p^T + b2 ----------------
// BM=128, BN=256, wave tile 64x64 (8 waves 2m x 4n), BK=32, 32 K-tiles.
// 3-slot LDS ring (24KB/slot = A 8KB + B 16KB, 72KB total) -> 2 blocks/CU.
// Staging: contiguous packed units, granule-permuted source (anti-bank-conflict
// swizzle applied in the source index; LDS dest linear). 3 gl_lds/thread/tile,
// prefetch distance 2, counted gate vmcnt(3) once per tile (T3/T4).
__global__ __launch_bounds__(512, 4) void gemm_pk(
        const short* __restrict__ Hp,   // [563*32 units][4096 shorts]
        const short* __restrict__ W2p,  // [4*32 units][8192 shorts]
        const float* __restrict__ b2,
        float* __restrict__ out)        // [M_TOT][V_]
{
    __shared__ __align__(16) char lds[3 * 24576];

    const int tid = threadIdx.x;
    const int lane = tid & 63;
    const int w = tid >> 6;            // 0..7
    const int wm = w >> 2, wn = w & 3; // 2m x 4n
    const int l15 = lane & 15, ksel = lane >> 4;

    // bijective XCD-aware swizzle
    const int nwg = gridDim.x;
    int bid = blockIdx.x;
    int q = nwg >> 3, r = nwg & 7;
    int xcd = bid & 7, lq = bid >> 3;
    int wg = (xcd < r ? xcd * (q + 1) : r * (q + 1) + (xcd - r) * q) + lq;
    const int mb = wg >> 2;            // 0..562
    const int nb = wg & 3;
    const int m0 = mb * 128, n0 = nb * 256;

    // staging source: thread stages granule gi=tid of each unit; the linear
    // LDS granule (row,g') must hold global granule g = g' ^ ((row>>1)&3),
    // so the source granule is permuted (unit stays contiguous 8/16KB).
    const int sr = tid >> 2;
    const int sg = (tid & 3) ^ ((sr >> 1) & 3);
    const short* aU = Hp + (long)mb * 32 * 4096 + sr * 32 + sg * 8;
    const short* bU = W2p + (long)nb * 32 * 8192 + sr * 32 + sg * 8;
    char* const ldsw = (char*)lds + (w << 10);   // wave-uniform dest base

#define STAGE_A(t_, sl_) gl_lds16(aU + (long)(t_) * 4096, ldsw + (sl_) * 24576)
#define STAGE_B(t_, sl_) do {                                               \
    char* db_ = ldsw + (sl_) * 24576 + 8192;                                \
    gl_lds16(bU + (long)(t_) * 8192, db_);                                  \
    gl_lds16(bU + (long)(t_) * 8192 + 4096, db_ + 8192);                    \
} while (0)

    f32x4 acc[4][4] = {};
    short8 af[4], bf[4];

#define PH_A(sl_, DOSTAGE, t2_, ss_) do {                                   \
    const char* Ab_ = (const char*)lds + (sl_) * 24576;                     \
    const char* Bb_ = Ab_ + 8192;                                           \
    _Pragma("unroll")                                                       \
    for (int nf = 0; nf < 2; ++nf) {                                        \
        int rw = wn * 64 + nf * 16 + l15;                                   \
        bf[nf] = *(const short8*)(Bb_ + rw * 64 + ((ksel ^ ((rw >> 1) & 3)) << 4)); \
    }                                                                       \
    _Pragma("unroll")                                                       \
    for (int mf = 0; mf < 4; ++mf) {                                        \
        int rw = wm * 64 + mf * 16 + l15;                                   \
        af[mf] = *(const short8*)(Ab_ + rw * 64 + ((ksel ^ ((rw >> 1) & 3)) << 4)); \
    }                                                                       \
    if (DOSTAGE) STAGE_A(t2_, ss_);                                         \
    __builtin_amdgcn_s_barrier();                                           \
    asm volatile("s_waitcnt lgkmcnt(0)" ::: "memory");                      \
    __builtin_amdgcn_s_setprio(1);                                          \
    _Pragma("unroll")                                                       \
    for (int nf = 0; nf < 2; ++nf)                                          \
        _Pragma("unroll")                                                   \
        for (int mf = 0; mf < 4; ++mf)                                      \
            acc[mf][nf] = __builtin_amdgcn_mfma_f32_16x16x32_bf16(          \
                af[mf], bf[nf], acc[mf][nf], 0, 0, 0);                      \
    __builtin_amdgcn_s_setprio(0);                                          \
    __builtin_amdgcn_s_barrier();                                           \
} while (0)

#define PH_B(sl_, DOSTAGE, t2_, ss_, GATE) do {                             \
    const char* Ab_ = (const char*)lds + (sl_) * 24576;                     \
    const char* Bb_ = Ab_ + 8192;                                           \
    _Pragma("unroll")                                                       \
    for (int nf = 2; nf < 4; ++nf) {                                        \
        int rw = wn * 64 + nf * 16 + l15;                                   \
        bf[nf] = *(const short8*)(Bb_ + rw * 64 + ((ksel ^ ((rw >> 1) & 3)) << 4)); \
    }                                                                       \
    if (DOSTAGE) STAGE_B(t2_, ss_);                                         \
    GATE                                                                    \
    __builtin_amdgcn_s_barrier();                                           \
    asm volatile("s_waitcnt lgkmcnt(0)" ::: "memory");                      \
    __builtin_amdgcn_s_setprio(1);                                          \
    _Pragma("unroll")                                                       \
    for (int nf = 2; nf < 4; ++nf)                                          \
        _Pragma("unroll")                                                   \
        for (int mf = 0; mf < 4; ++mf)                                      \
            acc[mf][nf] = __builtin_amdgcn_mfma_f32_16x16x32_bf16(          \
                af[mf], bf[nf], acc[mf][nf], 0, 0, 0);                      \
    __builtin_amdgcn_s_setprio(0);                                          \
    __builtin_amdgcn_s_barrier();                                           \
} while (0)

#define GATE3 asm volatile("s_waitcnt vmcnt(3)" ::: "memory");
#define GATE0 asm volatile("s_waitcnt vmcnt(0)" ::: "memory");
#define NOGATE

    // prologue: stage tiles 0,1; retire tile 0
    STAGE_A(0, 0); STAGE_B(0, 0);
    STAGE_A(1, 1); STAGE_B(1, 1);
    asm volatile("s_waitcnt vmcnt(3)" ::: "memory");
    __builtin_amdgcn_s_barrier();

    int s = 0, ss = 2;
#pragma unroll 1
    for (int t = 0; t < 30; ++t) {
        PH_A(s, true, t + 2, ss);
        PH_B(s, true, t + 2, ss, GATE3);
        s = (s == 2) ? 0 : s + 1;
        ss = (ss == 2) ? 0 : ss + 1;
    }
    // t = 30 (slot s), t = 31 (slot s+1)
    PH_A(s, false, 0, 0); PH_B(s, false, 0, 0, GATE0);
    s = (s == 2) ? 0 : s + 1;
    PH_A(s, false, 0, 0); PH_B(s, false, 0, 0, NOGATE);

    // epilogue: + b2, store fp32
#pragma unroll
    for (int nf = 0; nf < 4; ++nf) {
        int n = n0 + wn * 64 + nf * 16 + l15;
        if (n < V_) {
            float bv = b2[n];
#pragma unroll
            for (int mf = 0; mf < 4; ++mf)
#pragma unroll
                for (int j = 0; j < 4; ++j) {
                    int m = m0 + wm * 64 + mf * 16 + ksel * 4 + j;
                    if (m < M_TOT)
                        out[(long)m * V_ + n] = acc[mf][nf][j] + bv;
                }
        }
    }
#undef PH_A
#undef PH_B
#undef STAGE_A
#undef STAGE_B
#undef GATE3
#undef GATE0
#undef NOGATE
}

// ---------------- fallback fused kernel (only if ws too small) ----------------
__global__ __launch_bounds__(512, 2) void joint_gemm(
        const float* __restrict__ encP, const float* __restrict__ decP,
        const short* __restrict__ W2t, const float* __restrict__ b2,
        float* __restrict__ out)
{
    __shared__ short As[2][64 * 64];
    const int tid = threadIdx.x;
    const int lane = tid & 63;
    const int w = tid >> 6;
    const int m0 = blockIdx.x * 64;
    const int n0 = blockIdx.y * 512;

    const int arow = tid >> 3;
    const int k8 = tid & 7;
    const int am = m0 + arow;
    const int bt = am / U_;
    const int u = am - bt * U_;
    const int bidx = am / (T_ * U_);
    const float* eptr = encP + (long)bt * PK + k8 * 8;
    const float* dptr = decP + (long)(bidx * U_ + u) * PK + k8 * 8;
    const int wbyte = (arow * 128 + k8 * 16) ^ ((arow & 7) << 4);

    f32x4 acc[4][4] = {};
    const short* bbase[4];
#pragma unroll
    for (int nf = 0; nf < 4; ++nf) {
        int n = n0 + w * 64 + nf * 16 + (lane & 15);
        bbase[nf] = W2t + (long)n * WK + (lane >> 4) * 8;
    }
    f32x4 e0 = *(const f32x4*)(eptr), e1 = *(const f32x4*)(eptr + 4);
    f32x4 d0 = *(const f32x4*)(dptr), d1 = *(const f32x4*)(dptr + 4);
    {
        short vals[8];
#pragma unroll
        for (int j = 0; j < 4; ++j) vals[j]     = f2bf(fast_tanh(e0[j] + d0[j]));
#pragma unroll
        for (int j = 0; j < 4; ++j) vals[4 + j] = f2bf(fast_tanh(e1[j] + d1[j]));
        *(int4v*)((char*)&As[0][0] + wbyte) = *(const int4v*)vals;
    }
    e0 = *(const f32x4*)(eptr + 64); e1 = *(const f32x4*)(eptr + 68);
    d0 = *(const f32x4*)(dptr + 64); d1 = *(const f32x4*)(dptr + 68);
    asm volatile("s_waitcnt lgkmcnt(0)" ::: "memory");
    __builtin_amdgcn_s_barrier();

#pragma unroll 1
    for (int t = 0; t < 16; ++t) {
        const int k0 = t * 64;
        short8 bfr[2][4];
#pragma unroll
        for (int ks = 0; ks < 2; ++ks)
#pragma unroll
            for (int nf = 0; nf < 4; ++nf)
                bfr[ks][nf] = *(const short8*)(bbase[nf] + k0 + ks * 32);
        if (t < 15) {
            short vals[8];
#pragma unroll
            for (int j = 0; j < 4; ++j) vals[j]     = f2bf(fast_tanh(e0[j] + d0[j]));
#pragma unroll
            for (int j = 0; j < 4; ++j) vals[4 + j] = f2bf(fast_tanh(e1[j] + d1[j]));
            *(int4v*)((char*)&As[(t & 1) ^ 1][0] + wbyte) = *(const int4v*)vals;
            if (t < 14) {
                e0 = *(const f32x4*)(eptr + k0 + 128); e1 = *(const f32x4*)(eptr + k0 + 132);
                d0 = *(const f32x4*)(dptr + k0 + 128); d1 = *(const f32x4*)(dptr + k0 + 132);
            }
        }
        const char* rb = (const char*)&As[t & 1][0];
#pragma unroll
        for (int ks = 0; ks < 2; ++ks) {
            short8 af[4];
#pragma unroll
            for (int mf = 0; mf < 4; ++mf) {
                int row = mf * 16 + (lane & 15);
                int byte = (row * 128 + ks * 64 + (lane >> 4) * 16) ^ ((row & 7) << 4);
                af[mf] = *(const short8*)(rb + byte);
            }
#pragma unroll
            for (int nf = 0; nf < 4; ++nf)
#pragma unroll
                for (int mf = 0; mf < 4; ++mf)
                    acc[mf][nf] = __builtin_amdgcn_mfma_f32_16x16x32_bf16(
                        af[mf], bfr[ks][nf], acc[mf][nf], 0, 0, 0);
        }
        if (t < 15) {
            asm volatile("s_waitcnt lgkmcnt(0)" ::: "memory");
            __builtin_amdgcn_s_barrier();
        }
    }
#pragma unroll
    for (int nf = 0; nf < 4; ++nf) {
        int n = n0 + w * 64 + nf * 16 + (lane & 15);
        float bv = (n < V_) ? b2[n] : 0.f;
#pragma unroll
        for (int mf = 0; mf < 4; ++mf)
#pragma unroll
            for (int j = 0; j < 4; ++j) {
                int m = m0 + mf * 16 + (lane >> 4) * 4 + j;
                if (n < V_)
                    out[(long)m * V_ + n] = acc[mf][nf][j] + bv;
            }
    }
}

// ---------------- launch ----------------
extern "C" void kernel_launch(void* const* d_in, const int* in_sizes, int n_in,
                              void* d_out, int out_size, void* d_ws, size_t ws_size,
                              hipStream_t stream) {
    const float* enc = (const float*)d_in[0];
    const float* dec = (const float*)d_in[1];
    const float* W1  = (const float*)d_in[2];
    const float* b1  = (const float*)d_in[3];
    const float* W2  = (const float*)d_in[4];
    const float* b2  = (const float*)d_in[5];
    float* out = (float*)d_out;

    char* ws = (char*)d_ws;
    size_t off = 0;
    short* W1t  = (short*)(ws + off); off += (size_t)1024 * WK * 2;          // 2.06 MB
    short* W2p  = (short*)(ws + off); off += (size_t)4 * 32 * 8192 * 2;      // 2.10 MB
    float* encP = (float*)(ws + off); off += (size_t)1200 * PK * 4;          // 4.99 MB
    float* decP = (float*)(ws + off); off += (size_t)240 * PK * 4;           // 1.00 MB
    short* Hp   = (short*)(ws + off);
    size_t need = off + (size_t)MB_CNT * 32 * 4096 * 2;                      // +147.6 MB

    transpose_cvt<<<dim3(16, 16), 256, 0, stream>>>(W1, W1t, 1024, 1024, WK);
    proj_gemm<<<dim3(19, 16), 256, 0, stream>>>(enc, 1200, 0,   W1t, nullptr, encP);
    proj_gemm<<<dim3(4, 16),  256, 0, stream>>>(dec, 240,  512, W1t, b1,      decP);

    if (ws_size >= need) {
        transpose_pack_w2<<<dim3(16, 16), 256, 0, stream>>>(W2, W2p);
        hgen_pk<<<MB_CNT * 32 * 512 / 256, 256, 0, stream>>>(encP, decP, Hp);
        gemm_pk<<<MB_CNT * 4, 512, 0, stream>>>(Hp, W2p, b2, out);
    } else {
        // fallback: fused kernel with W2 in old transposed layout (reuse W2p space
        // is too small for [1024][WK]; put it after decP if it fits, else W2p slot)
        short* W2t = W2p;  // 2.10 MB slot; need 1024*WK*2 = 2.06 MB -> fits
        transpose_cvt<<<dim3(16, 16), 256, 0, stream>>>(W2, W2t, 1024, 1000, WK);
        joint_gemm<<<dim3(1125, 2), 512, 0, stream>>>(encP, decP, W2t, b2, out);
    }
}

// Round 9
// 339.680 us; speedup vs baseline: 1.2946x; 1.0669x over previous
//
#include <hip/hip_runtime.h>
#include <hip/hip_bf16.h>
#include <stdint.h>

#define B_  4
#define T_  300
#define U_  60
#define V_  1000
#define M_TOT (B_*T_*U_)   // 72000
#define MBCNT 282          // ceil(72000/256)
#define WK  1056           // padded W1t row stride (shorts)
#define PK  1040           // padded proj row stride (floats)

typedef __attribute__((ext_vector_type(8))) short short8;
typedef __attribute__((ext_vector_type(4))) float f32x4;
typedef __attribute__((ext_vector_type(4))) int int4v;

__device__ __forceinline__ short f2bf(float f) {
    union { float f; uint32_t u; } c; c.f = f;
    uint32_t u = c.u;
    uint32_t r = (u + 0x7FFFu + ((u >> 16) & 1u)) >> 16;
    return (short)r;
}

__device__ __forceinline__ float fast_tanh(float x) {
    float e = __expf(2.0f * x);
    float r = __builtin_amdgcn_rcpf(e + 1.0f);
    return 1.0f - 2.0f * r;
}

__device__ __forceinline__ void gl_lds16(const void* g, void* l) {
    __builtin_amdgcn_global_load_lds(
        (const __attribute__((address_space(1))) void*)g,
        (__attribute__((address_space(3))) void*)l, 16, 0, 0);
}

// ---------------- prep kernels ----------------

// fp32 [R][C] -> bf16 [C][R] with row stride ostride (used for W1)
__global__ void transpose_cvt(const float* __restrict__ in, short* __restrict__ out,
                              int R, int C, int ostride) {
    __shared__ float tile[64][65];
    const int tx = threadIdx.x & 63, ty = threadIdx.x >> 6;
    const int r0 = blockIdx.y * 64, c0 = blockIdx.x * 64;
#pragma unroll
    for (int i = 0; i < 16; ++i) {
        int r = r0 + i * 4 + ty, c = c0 + tx;
        float v = 0.f;
        if (r < R && c < C) v = in[(long)r * C + c];
        tile[i * 4 + ty][tx] = v;
    }
    __syncthreads();
#pragma unroll
    for (int i = 0; i < 16; ++i) {
        int oc = c0 + i * 4 + ty;
        int orr = r0 + tx;
        out[(long)oc * ostride + orr] = f2bf(tile[tx][i * 4 + ty]);
    }
}

// W2 [1024 k][1000 v] -> half-tile units: unit(nb,t,h)=((nb*16+t)*2+h) of
// 128 rows x 64 k (16KB), plain row-major within unit.
__global__ void transpose_pack_w2(const float* __restrict__ in, short* __restrict__ out) {
    __shared__ float tile[64][65];
    const int tx = threadIdx.x & 63, ty = threadIdx.x >> 6;
    const int r0 = blockIdx.y * 64, c0 = blockIdx.x * 64;   // r=k, c=v
#pragma unroll
    for (int i = 0; i < 16; ++i) {
        int r = r0 + i * 4 + ty, c = c0 + tx;
        float v = 0.f;
        if (c < V_) v = in[(long)r * V_ + c];
        tile[i * 4 + ty][tx] = v;
    }
    __syncthreads();
#pragma unroll
    for (int i = 0; i < 16; ++i) {
        int oc = c0 + i * 4 + ty;       // v 0..1023
        int orr = r0 + tx;              // k 0..1023
        int nb = oc >> 8, pr = oc & 255, h = pr >> 7, rr = pr & 127;
        int t = orr >> 6, kk = orr & 63;
        out[(long)((nb * 16 + t) * 2 + h) * 8192 + rr * 64 + kk] =
            f2bf(tile[tx][i * 4 + ty]);
    }
}

// P[M][PK] = bf16(X[M][512]) @ W1t[k_off:k_off+512]^T (+ b1)
__global__ __launch_bounds__(256, 2) void proj_gemm(
        const float* __restrict__ X, int M, int k_off,
        const short* __restrict__ Wt,
        const float* __restrict__ b1,
        float* __restrict__ P)
{
    __shared__ short As[64 * 64];
    const int tid = threadIdx.x;
    const int lane = tid & 63;
    const int w = tid >> 6;
    const int wm = w >> 1, wn = w & 1;
    const int m0 = blockIdx.x * 64, n0 = blockIdx.y * 64;

    f32x4 acc[2][2] = {};
    for (int k0 = 0; k0 < 512; k0 += 64) {
#pragma unroll
        for (int c = 0; c < 2; ++c) {
            int lin = tid + 256 * c;
            int row = lin >> 3, k8 = lin & 7;
            int m = m0 + row;
            short vals[8];
            if (m < M) {
                const float* xp = X + (long)m * 512 + k0 + k8 * 8;
#pragma unroll
                for (int j = 0; j < 8; ++j) vals[j] = f2bf(xp[j]);
            } else {
#pragma unroll
                for (int j = 0; j < 8; ++j) vals[j] = 0;
            }
            int byte = row * 128 + k8 * 16;
            byte ^= (row & 7) << 4;
            *(int4v*)((char*)As + byte) = *(const int4v*)vals;
        }
        __syncthreads();
#pragma unroll
        for (int ks = 0; ks < 2; ++ks) {
            short8 af[2];
#pragma unroll
            for (int mf = 0; mf < 2; ++mf) {
                int row = wm * 32 + mf * 16 + (lane & 15);
                int byte = row * 128 + ks * 64 + (lane >> 4) * 16;
                byte ^= (row & 7) << 4;
                af[mf] = *(const short8*)((char*)As + byte);
            }
#pragma unroll
            for (int nf = 0; nf < 2; ++nf) {
                int h = n0 + wn * 32 + nf * 16 + (lane & 15);
                const short* bp = Wt + (long)h * WK + k_off + k0 + ks * 32 + (lane >> 4) * 8;
                short8 bfv = *(const short8*)bp;
#pragma unroll
                for (int mf = 0; mf < 2; ++mf)
                    acc[mf][nf] = __builtin_amdgcn_mfma_f32_16x16x32_bf16(af[mf], bfv, acc[mf][nf], 0, 0, 0);
            }
        }
        __syncthreads();
    }
#pragma unroll
    for (int mf = 0; mf < 2; ++mf)
#pragma unroll
        for (int nf = 0; nf < 2; ++nf) {
            int h = n0 + wn * 32 + nf * 16 + (lane & 15);
            float bb = b1 ? b1[h] : 0.f;
#pragma unroll
            for (int j = 0; j < 4; ++j) {
                int m = m0 + wm * 32 + mf * 16 + (lane >> 4) * 4 + j;
                if (m < M) P[(long)m * PK + h] = acc[mf][nf][j] + bb;
            }
        }
}

// ---------------- packed H: unit(mb,t,h)=((mb*16+t)*2+h), 128x64 (16KB) ------
__global__ __launch_bounds__(256) void hgen_pk(
        const float* __restrict__ encP, const float* __restrict__ decP,
        short* __restrict__ Hp)
{
    long idx = (long)blockIdx.x * 256 + threadIdx.x;
    int u = (int)(idx >> 10);
    int gi = (int)(idx & 1023);
    int mb = u >> 5, rem = u & 31, t = rem >> 1, h = rem & 1;
    int r = gi >> 3, kg = gi & 7;
    int m = mb * 256 + h * 128 + r;
    int k = t * 64 + kg * 8;
    short8 v = {};
    if (m < M_TOT) {
        int bt = m / U_;
        int uu = m - bt * U_;
        int b = m / (T_ * U_);
        const float* e = encP + (long)bt * PK + k;
        const float* d = decP + (long)(b * U_ + uu) * PK + k;
        f32x4 e0 = *(const f32x4*)(e), e1 = *(const f32x4*)(e + 4);
        f32x4 d0 = *(const f32x4*)(d), d1 = *(const f32x4*)(d + 4);
#pragma unroll
        for (int j = 0; j < 4; ++j) v[j]     = f2bf(fast_tanh(e0[j] + d0[j]));
#pragma unroll
        for (int j = 0; j < 4; ++j) v[4 + j] = f2bf(fast_tanh(e1[j] + d1[j]));
    }
    *(short8*)(Hp + (long)u * 8192 + gi * 8) = v;
}

// ---------------- main GEMM: 256x256, BK=64, 8-phase template port ----------
// 8 waves (2m x 4n), wave tile 128x64 split into quadrants (qm,qn); 4 phases
// per K-tile, 16 MFMA each. LDS [2 dbuf][A0,A1,B0,B1] 16KB halves = 128KB.
// Stage 1 half/phase, 5 halves ahead; counted vmcnt(6) gates (drain only at
// the final tile). Source-side XOR (row&7) granule perm paired with the same
// XOR on ds_read.
__global__ __launch_bounds__(512, 2) void gemm8p(
        const short* __restrict__ Hp,   // units (mb,t,h)
        const short* __restrict__ W2p,  // units (nb,t,h)
        const float* __restrict__ b2,
        float* __restrict__ out)        // [M_TOT][V_]
{
    __shared__ __align__(16) char lds[131072];

    const int tid = threadIdx.x;
    const int lane = tid & 63;
    const int w = tid >> 6;
    const int wm = w >> 2, wn = w & 3;
    const int l15 = lane & 15, ksel = lane >> 4;

    // bijective XCD swizzle (nwg = 1128 = 8*141)
    const int nwg = gridDim.x;
    int bid = blockIdx.x;
    int q = nwg >> 3, r = nwg & 7;
    int xcd = bid & 7, lq = bid >> 3;
    int wg = (xcd < r ? xcd * (q + 1) : r * (q + 1) + (xcd - r) * q) + lq;
    const int mb = wg >> 2, nb = wg & 3;

    // staging: thread -> granule gi=tid (rows 0..63) and gi=512+tid (rows 64..127)
    // of each 16KB half-unit; source granule permuted g = (tid&7) ^ (row&7).
    const int rowA = tid >> 3;
    const int gA = (tid & 7) ^ (rowA & 7);
    const short* aSrc = Hp  + (long)mb * 262144 + rowA * 64 + gA * 8;
    const short* bSrc = W2p + (long)nb * 262144 + rowA * 64 + gA * 8;
    const int wq = w << 10;   // wave-uniform dest offset within a half region

#define ST_A(uidx_, roff_) do {                                              \
    gl_lds16(aSrc + (long)(uidx_) * 8192, (char*)lds + (roff_) + wq);        \
    gl_lds16(aSrc + (long)(uidx_) * 8192 + 4096,                             \
             (char*)lds + (roff_) + 8192 + wq);                              \
} while (0)
#define ST_B(uidx_, roff_) do {                                              \
    gl_lds16(bSrc + (long)(uidx_) * 8192, (char*)lds + (roff_) + wq);        \
    gl_lds16(bSrc + (long)(uidx_) * 8192 + 4096,                             \
             (char*)lds + (roff_) + 8192 + wq);                              \
} while (0)

    short8 af[4][2], bf0[2][2], bf1[2][2];
    f32x4 acc[8][4] = {};

#define RD_AF(d_, qm_) do {                                                  \
    _Pragma("unroll")                                                        \
    for (int mf = 0; mf < 4; ++mf) {                                         \
        const int rw_ = wm * 64 + mf * 16 + l15;                             \
        const char* bp_ = (const char*)lds + (d_) * 65536 + (qm_) * 16384    \
                          + rw_ * 128;                                       \
        const int sx_ = (rw_ & 7) << 4;                                      \
        af[mf][0] = *(const short8*)(bp_ + ((ksel * 16) ^ sx_));             \
        af[mf][1] = *(const short8*)(bp_ + ((64 + ksel * 16) ^ sx_));        \
    } } while (0)

#define RD_BF(d_, qn_, B_) do {                                              \
    _Pragma("unroll")                                                        \
    for (int nf = 0; nf < 2; ++nf) {                                         \
        const int rw_ = wn * 32 + nf * 16 + l15;                             \
        const char* bp_ = (const char*)lds + (d_) * 65536 + 32768            \
                          + (qn_) * 16384 + rw_ * 128;                       \
        const int sx_ = (rw_ & 7) << 4;                                      \
        B_[nf][0] = *(const short8*)(bp_ + ((ksel * 16) ^ sx_));             \
        B_[nf][1] = *(const short8*)(bp_ + ((64 + ksel * 16) ^ sx_));        \
    } } while (0)

#define MM(qm_, qn_, B_) do {                                                \
    __builtin_amdgcn_s_setprio(1);                                           \
    _Pragma("unroll")                                                        \
    for (int kh = 0; kh < 2; ++kh)                                           \
        _Pragma("unroll")                                                    \
        for (int nf = 0; nf < 2; ++nf)                                       \
            _Pragma("unroll")                                                \
            for (int mf = 0; mf < 4; ++mf)                                   \
                acc[(qm_) * 4 + mf][(qn_) * 2 + nf] =                        \
                    __builtin_amdgcn_mfma_f32_16x16x32_bf16(                 \
                        af[mf][kh], B_[nf][kh],                              \
                        acc[(qm_) * 4 + mf][(qn_) * 2 + nf], 0, 0, 0);       \
    __builtin_amdgcn_s_setprio(0);                                           \
} while (0)

#define GATE(n_) asm volatile("s_waitcnt vmcnt(" #n_ ")" ::: "memory")
#define BARC do {                                                            \
    __builtin_amdgcn_s_barrier();                                            \
    asm volatile("s_waitcnt lgkmcnt(0)" ::: "memory");                       \
    __builtin_amdgcn_sched_barrier(0);                                       \
} while (0)
#define BARE __builtin_amdgcn_s_barrier()

#define TILE(t_, c_, n_, G3_) do {                                           \
    /* p0: quadrant (0,0) */                                                 \
    RD_AF(c_, 0); RD_BF(c_, 0, bf0);                                         \
    ST_B(((t_) + 1) * 2,     (n_) * 65536 + 32768);                          \
    GATE(6);                                                                 \
    asm volatile("s_waitcnt lgkmcnt(8)" ::: "memory");                       \
    BARC; MM(0, 0, bf0); BARE;                                               \
    /* p1: (0,1) */                                                          \
    RD_BF(c_, 1, bf1);                                                       \
    ST_B(((t_) + 1) * 2 + 1, (n_) * 65536 + 49152);                          \
    GATE(6);                                                                 \
    BARC; MM(0, 1, bf1); BARE;                                               \
    /* p2: (1,0) */                                                          \
    RD_AF(c_, 1);                                                            \
    ST_A(((t_) + 1) * 2 + 1, (n_) * 65536 + 16384);                          \
    BARC; MM(1, 0, bf0); BARE;                                               \
    /* p3: (1,1) */                                                          \
    ST_A(((t_) + 2) * 2,     (c_) * 65536);                                  \
    G3_;                                                                     \
    BARC; MM(1, 1, bf1); BARE;                                               \
} while (0)

    // prologue: halves H0..H4 = {A0,B0,B1,A1}(t0), A0(t1); gate; barrier
    ST_A(0, 0);
    ST_B(0, 32768);
    ST_B(1, 49152);
    ST_A(1, 16384);
    ST_A(2, 65536);
    GATE(6);
    BARE;

#pragma unroll 1
    for (int tt = 0; tt < 14; tt += 2) {
        TILE(tt,     0, 1, GATE(6));
        TILE(tt + 1, 1, 0, GATE(6));
    }
    // tile 14 (cur=0): stages 61,62,63; p3 no stage, gate vmcnt(4)
    RD_AF(0, 0); RD_BF(0, 0, bf0);
    ST_B(30, 65536 + 32768);
    GATE(6);
    asm volatile("s_waitcnt lgkmcnt(8)" ::: "memory");
    BARC; MM(0, 0, bf0); BARE;
    RD_BF(0, 1, bf1);
    ST_B(31, 65536 + 49152);
    GATE(6);
    BARC; MM(0, 1, bf1); BARE;
    RD_AF(0, 1);
    ST_A(31, 65536 + 16384);
    BARC; MM(1, 0, bf0); BARE;
    GATE(4);
    BARC; MM(1, 1, bf1); BARE;
    // tile 15 (cur=1): no stages; gates 2, 0
    RD_AF(1, 0); RD_BF(1, 0, bf0);
    GATE(2);
    BARC; MM(0, 0, bf0); BARE;
    RD_BF(1, 1, bf1);
    GATE(0);
    BARC; MM(0, 1, bf1); BARE;
    RD_AF(1, 1);
    BARC; MM(1, 0, bf0); BARE;
    BARC; MM(1, 1, bf1);

    // epilogue: + b2, store fp32
#pragma unroll
    for (int qn = 0; qn < 2; ++qn)
#pragma unroll
        for (int nf = 0; nf < 2; ++nf) {
            int n = nb * 256 + qn * 128 + wn * 32 + nf * 16 + l15;
            if (n < V_) {
                float bv = b2[n];
#pragma unroll
                for (int qm = 0; qm < 2; ++qm)
#pragma unroll
                    for (int mf = 0; mf < 4; ++mf)
#pragma unroll
                        for (int j = 0; j < 4; ++j) {
                            int m = mb * 256 + qm * 128 + wm * 64 + mf * 16 + ksel * 4 + j;
                            if (m < M_TOT)
                                out[(long)m * V_ + n] = acc[qm * 4 + mf][qn * 2 + nf][j] + bv;
                        }
            }
        }
#undef ST_A
#undef ST_B
#undef RD_AF
#undef RD_BF
#undef MM
#undef GATE
#undef BARC
#undef BARE
#undef TILE
}

// ---------------- fallback fused kernel (only if ws too small) ----------------
__global__ __launch_bounds__(512, 2) void joint_gemm(
        const float* __restrict__ encP, const float* __restrict__ decP,
        const short* __restrict__ W2t, const float* __restrict__ b2,
        float* __restrict__ out)
{
    __shared__ short As[2][64 * 64];
    const int tid = threadIdx.x;
    const int lane = tid & 63;
    const int w = tid >> 6;
    const int m0 = blockIdx.x * 64;
    const int n0 = blockIdx.y * 512;

    const int arow = tid >> 3;
    const int k8 = tid & 7;
    const int am = m0 + arow;
    const int bt = am / U_;
    const int u = am - bt * U_;
    const int bidx = am / (T_ * U_);
    const float* eptr = encP + (long)bt * PK + k8 * 8;
    const float* dptr = decP + (long)(bidx * U_ + u) * PK + k8 * 8;
    const int wbyte = (arow * 128 + k8 * 16) ^ ((arow & 7) << 4);

    f32x4 acc[4][4] = {};
    const short* bbase[4];
#pragma unroll
    for (int nf = 0; nf < 4; ++nf) {
        int n = n0 + w * 64 + nf * 16 + (lane & 15);
        bbase[nf] = W2t + (long)n * WK + (lane >> 4) * 8;
    }
    f32x4 e0 = *(const f32x4*)(eptr), e1 = *(const f32x4*)(eptr + 4);
    f32x4 d0 = *(const f32x4*)(dptr), d1 = *(const f32x4*)(dptr + 4);
    {
        short vals[8];
#pragma unroll
        for (int j = 0; j < 4; ++j) vals[j]     = f2bf(fast_tanh(e0[j] + d0[j]));
#pragma unroll
        for (int j = 0; j < 4; ++j) vals[4 + j] = f2bf(fast_tanh(e1[j] + d1[j]));
        *(int4v*)((char*)&As[0][0] + wbyte) = *(const int4v*)vals;
    }
    e0 = *(const f32x4*)(eptr + 64); e1 = *(const f32x4*)(eptr + 68);
    d0 = *(const f32x4*)(dptr + 64); d1 = *(const f32x4*)(dptr + 68);
    asm volatile("s_waitcnt lgkmcnt(0)" ::: "memory");
    __builtin_amdgcn_s_barrier();

#pragma unroll 1
    for (int t = 0; t < 16; ++t) {
        const int k0 = t * 64;
        short8 bfr[2][4];
#pragma unroll
        for (int ks = 0; ks < 2; ++ks)
#pragma unroll
            for (int nf = 0; nf < 4; ++nf)
                bfr[ks][nf] = *(const short8*)(bbase[nf] + k0 + ks * 32);
        if (t < 15) {
            short vals[8];
#pragma unroll
            for (int j = 0; j < 4; ++j) vals[j]     = f2bf(fast_tanh(e0[j] + d0[j]));
#pragma unroll
            for (int j = 0; j < 4; ++j) vals[4 + j] = f2bf(fast_tanh(e1[j] + d1[j]));
            *(int4v*)((char*)&As[(t & 1) ^ 1][0] + wbyte) = *(const int4v*)vals;
            if (t < 14) {
                e0 = *(const f32x4*)(eptr + k0 + 128); e1 = *(const f32x4*)(eptr + k0 + 132);
                d0 = *(const f32x4*)(dptr + k0 + 128); d1 = *(const f32x4*)(dptr + k0 + 132);
            }
        }
        const char* rb = (const char*)&As[t & 1][0];
#pragma unroll
        for (int ks = 0; ks < 2; ++ks) {
            short8 af[4];
#pragma unroll
            for (int mf = 0; mf < 4; ++mf) {
                int row = mf * 16 + (lane & 15);
                int byte = (row * 128 + ks * 64 + (lane >> 4) * 16) ^ ((row & 7) << 4);
                af[mf] = *(const short8*)(rb + byte);
            }
#pragma unroll
            for (int nf = 0; nf < 4; ++nf)
#pragma unroll
                for (int mf = 0; mf < 4; ++mf)
                    acc[mf][nf] = __builtin_amdgcn_mfma_f32_16x16x32_bf16(
                        af[mf], bfr[ks][nf], acc[mf][nf], 0, 0, 0);
        }
        if (t < 15) {
            asm volatile("s_waitcnt lgkmcnt(0)" ::: "memory");
            __builtin_amdgcn_s_barrier();
        }
    }
#pragma unroll
    for (int nf = 0; nf < 4; ++nf) {
        int n = n0 + w * 64 + nf * 16 + (lane & 15);
        float bv = (n < V_) ? b2[n] : 0.f;
#pragma unroll
        for (int mf = 0; mf < 4; ++mf)
#pragma unroll
            for (int j = 0; j < 4; ++j) {
                int m = m0 + mf * 16 + (lane >> 4) * 4 + j;
                if (n < V_)
                    out[(long)m * V_ + n] = acc[mf][nf][j] + bv;
            }
    }
}

// ---------------- launch ----------------
extern "C" void kernel_launch(void* const* d_in, const int* in_sizes, int n_in,
                              void* d_out, int out_size, void* d_ws, size_t ws_size,
                              hipStream_t stream) {
    const float* enc = (const float*)d_in[0];
    const float* dec = (const float*)d_in[1];
    const float* W1  = (const float*)d_in[2];
    const float* b1  = (const float*)d_in[3];
    const float* W2  = (const float*)d_in[4];
    const float* b2  = (const float*)d_in[5];
    float* out = (float*)d_out;

    char* ws = (char*)d_ws;
    size_t off = 0;
    short* W1t  = (short*)(ws + off); off += (size_t)1024 * WK * 2;          // 2.06 MB
    short* W2p  = (short*)(ws + off); off += (size_t)1024 * WK * 2;          // slot fits both layouts
    float* encP = (float*)(ws + off); off += (size_t)1200 * PK * 4;          // 4.99 MB
    float* decP = (float*)(ws + off); off += (size_t)240 * PK * 4;           // 1.00 MB
    short* Hp   = (short*)(ws + off);
    size_t need = off + (size_t)MBCNT * 262144 * 2;                          // +147.8 MB

    transpose_cvt<<<dim3(16, 16), 256, 0, stream>>>(W1, W1t, 1024, 1024, WK);
    proj_gemm<<<dim3(19, 16), 256, 0, stream>>>(enc, 1200, 0,   W1t, nullptr, encP);
    proj_gemm<<<dim3(4, 16),  256, 0, stream>>>(dec, 240,  512, W1t, b1,      decP);

    if (ws_size >= need) {
        transpose_pack_w2<<<dim3(16, 16), 256, 0, stream>>>(W2, W2p);
        hgen_pk<<<MBCNT * 32 * 1024 / 256, 256, 0, stream>>>(encP, decP, Hp);
        gemm8p<<<MBCNT * 4, 512, 0, stream>>>(Hp, W2p, b2, out);
    } else {
        short* W2t = W2p;
        transpose_cvt<<<dim3(16, 16), 256, 0, stream>>>(W2, W2t, 1024, 1000, WK);
        joint_gemm<<<dim3(1125, 2), 512, 0, stream>>>(encP, decP, W2t, b2, out);
    }
}